// Round 1
// 679.674 us; speedup vs baseline: 1.0098x; 1.0098x over previous
//
#include <hip/hip_runtime.h>
#include <math.h>

// Problem: factor [65536, 2048] fp32.
//   f = row-L2-normalize(factor)  (torch F.normalize, eps=1e-12)
//   adj[i] = <f_i, f_{i+1}>, out = -WEIGHT * 2 * mean(adj)   (single fp32 scalar)
//
// Pass 1: single streaming pass, per-row sum-of-squares + consecutive-row dots.
//   Restructured vs previous version: fully unrolled 16-row chunk with even/odd
//   register rotation (no data-dependent break, clamped boundary addressing) and
//   ONE batched end-of-chunk butterfly reduction (32 independent 6-step chains)
//   instead of a serial 12-shfl chain per row. This removes the per-row
//   issue->vmcnt(0)->reduce serialization so loads for row r+1 pipeline under
//   row r's FMAs; the kernel should be HBM-bound (~90-120 us for 545 MB).
// Pass 2: tiny fp64 reduction over 65535 pairs (unchanged, bit-identical).

#define N_ROWS 65536
#define N_COLS 2048
#define RPW 16   // rows per wave; 6.25% boundary re-read; 4096 waves = 16/CU

__global__ __launch_bounds__(256) void tcr_pass1(const float* __restrict__ x,
                                                 float* __restrict__ sq,
                                                 float* __restrict__ cross) {
    const int wid  = (blockIdx.x * 256 + threadIdx.x) >> 6;   // global wave id
    const int lane = threadIdx.x & 63;
    const int r0   = wid * RPW;
    const float4* __restrict__ rowp = (const float4*)x;  // row r = float4 idx [r*512, r*512+512)

    // Row buffers: lane covers float4 indices lane + k*64, k=0..7 (1 KiB/instr, coalesced).
    float4 A[8], B[8];
    {
        const int b = r0 * 512 + lane;
        #pragma unroll
        for (int k = 0; k < 8; ++k) A[k] = rowp[b + k * 64];
    }

    float sqv[RPW];   // per-lane partial ||row r0+i||^2
    float crv[RPW];   // per-lane partial <row r0+i, row r0+i+1>

    #pragma unroll
    for (int i = 0; i < RPW; i += 2) {
        // A holds row r0+i. Load row r0+i+1 into B (clamp: last wave's boundary
        // row 65536 doesn't exist; duplicate row 65535 -> cross[65535] garbage,
        // never read by pass2 which stops at i < N_ROWS-1).
        {
            int rr = r0 + i + 1; if (rr > N_ROWS - 1) rr = N_ROWS - 1;
            const int b = rr * 512 + lane;
            #pragma unroll
            for (int k = 0; k < 8; ++k) B[k] = rowp[b + k * 64];
        }
        {
            float s = 0.f, c = 0.f;
            #pragma unroll
            for (int k = 0; k < 8; ++k) {
                s += A[k].x * A[k].x + A[k].y * A[k].y + A[k].z * A[k].z + A[k].w * A[k].w;
                c += A[k].x * B[k].x + A[k].y * B[k].y + A[k].z * B[k].z + A[k].w * B[k].w;
            }
            sqv[i] = s; crv[i] = c;
        }
        // B holds row r0+i+1. Load row r0+i+2 into A.
        {
            int rr = r0 + i + 2; if (rr > N_ROWS - 1) rr = N_ROWS - 1;
            const int b = rr * 512 + lane;
            #pragma unroll
            for (int k = 0; k < 8; ++k) A[k] = rowp[b + k * 64];
        }
        {
            float s = 0.f, c = 0.f;
            #pragma unroll
            for (int k = 0; k < 8; ++k) {
                s += B[k].x * B[k].x + B[k].y * B[k].y + B[k].z * B[k].z + B[k].w * B[k].w;
                c += B[k].x * A[k].x + B[k].y * A[k].y + B[k].z * A[k].z + B[k].w * A[k].w;
            }
            sqv[i + 1] = s; crv[i + 1] = c;
        }
    }

    // Batched butterfly: 32 independent 6-step chains (pipelined, ~once per 128 KiB
    // streamed). Same per-value offset order (32..1) as before -> bit-identical.
    #pragma unroll
    for (int off = 32; off; off >>= 1) {
        #pragma unroll
        for (int i = 0; i < RPW; ++i) {
            sqv[i] += __shfl_xor(sqv[i], off, 64);
            crv[i] += __shfl_xor(crv[i], off, 64);
        }
    }
    if (lane == 0) {
        #pragma unroll
        for (int i = 0; i < RPW; ++i) {
            sq[r0 + i]    = sqv[i];
            cross[r0 + i] = crv[i];
        }
    }
}

// Final reduction: sum cross[i] / (max(sqrt(sq[i]),eps) * max(sqrt(sq[i+1]),eps)),
// scale, atomic-accumulate into the fp32 scalar output. fp64 accumulation: the
// sum has heavy cancellation (65535 terms ~±0.02 netting ~0.4). UNCHANGED.
__global__ __launch_bounds__(256) void tcr_pass2(const float* __restrict__ sq,
                                                 const float* __restrict__ cross,
                                                 float* __restrict__ out) {
    const int tid    = blockIdx.x * 256 + threadIdx.x;
    const int stride = gridDim.x * 256;
    double acc = 0.0;
    for (int i = tid; i < N_ROWS - 1; i += stride) {
        double ni = fmax(sqrt((double)sq[i]),     1e-12);
        double nj = fmax(sqrt((double)sq[i + 1]), 1e-12);
        acc += (double)cross[i] / (ni * nj);
    }
    __shared__ double sd[256];
    sd[threadIdx.x] = acc;
    __syncthreads();
    for (int s = 128; s; s >>= 1) {
        if (threadIdx.x < s) sd[threadIdx.x] += sd[threadIdx.x + s];
        __syncthreads();
    }
    if (threadIdx.x == 0) {
        // out = -WEIGHT * (p1 + p2) = -0.01 * 2 * sum/(N-1)
        double partial = sd[0] * (-2.0 * 0.01 / (double)(N_ROWS - 1));
        atomicAdd(out, (float)partial);
    }
}

extern "C" void kernel_launch(void* const* d_in, const int* in_sizes, int n_in,
                              void* d_out, int out_size, void* d_ws, size_t ws_size,
                              hipStream_t stream) {
    const float* factor = (const float*)d_in[0];
    float* out = (float*)d_out;

    // Workspace layout: sq[N_ROWS] floats, then cross[N_ROWS] floats (cross[N-1] unused).
    float* sq    = (float*)d_ws;
    float* cross = sq + N_ROWS;

    // Pass 1: 65536 rows / 16 rows-per-wave = 4096 waves = 1024 blocks of 4 waves.
    const int n_waves  = N_ROWS / RPW;
    const int n_blocks = n_waves / 4;
    tcr_pass1<<<n_blocks, 256, 0, stream>>>(factor, sq, cross);

    // Zero the output scalar (harness poisons it to 0xAA before every timed call).
    hipMemsetAsync(d_out, 0, sizeof(float), stream);

    // Pass 2: tiny reduction over 65535 pairs.
    tcr_pass2<<<64, 256, 0, stream>>>(sq, cross, out);
}

// Round 2
// 657.021 us; speedup vs baseline: 1.0447x; 1.0345x over previous
//
#include <hip/hip_runtime.h>
#include <math.h>

// Problem: factor [65536, 2048] fp32.
//   f = row-L2-normalize(factor)  (torch F.normalize, eps=1e-12)
//   adj[i] = <f_i, f_{i+1}>, out = -WEIGHT * 2 * mean(adj)   (single fp32 scalar)
//
// Round-2 theory: pass1 is pinned at ~1.6 TB/s independent of code structure.
// The harness's 2-GiB workspace poison-fill runs immediately before pass1 every
// iteration, leaving L2+L3 entirely dirty; pass1's streaming reads then pay a
// dirty-victim writeback/allocation cascade per line. Fix: NONTEMPORAL loads
// (no cache allocation -> no eviction cascade). The fill also scrubs any input
// L3 residency, so nt loses no reuse. Also RPW 16->8 for finer balance and a
// shorter per-wave serial chain (+3.4% boundary traffic, ~6 us at roofline).
// Numerics bit-identical to the passing kernel (same FMA order, same butterfly
// order, same pass2).

#define N_ROWS 65536
#define N_COLS 2048
#define RPW 8   // rows per wave; 12.5% boundary re-read; 8192 waves

typedef float v4f __attribute__((ext_vector_type(4)));

__device__ __forceinline__ v4f ntload(const v4f* p) {
    return __builtin_nontemporal_load(p);
}

__global__ __launch_bounds__(256) void tcr_pass1(const float* __restrict__ x,
                                                 float* __restrict__ sq,
                                                 float* __restrict__ cross) {
    const int wid  = (blockIdx.x * 256 + threadIdx.x) >> 6;   // global wave id
    const int lane = threadIdx.x & 63;
    const int r0   = wid * RPW;
    const v4f* __restrict__ rowp = (const v4f*)x;  // row r = v4f idx [r*512, r*512+512)

    // Row buffers: lane covers v4f indices lane + k*64, k=0..7 (1 KiB/instr, coalesced).
    v4f A[8], B[8];
    {
        const int b = r0 * 512 + lane;
        #pragma unroll
        for (int k = 0; k < 8; ++k) A[k] = ntload(&rowp[b + k * 64]);
    }

    float sqv[RPW];   // per-lane partial ||row r0+i||^2
    float crv[RPW];   // per-lane partial <row r0+i, row r0+i+1>

    #pragma unroll
    for (int i = 0; i < RPW; i += 2) {
        // A holds row r0+i. Load row r0+i+1 into B (clamp: duplicate last row at
        // the global boundary -> cross[65535] garbage, never read by pass2).
        {
            int rr = r0 + i + 1; if (rr > N_ROWS - 1) rr = N_ROWS - 1;
            const int b = rr * 512 + lane;
            #pragma unroll
            for (int k = 0; k < 8; ++k) B[k] = ntload(&rowp[b + k * 64]);
        }
        {
            float s = 0.f, c = 0.f;
            #pragma unroll
            for (int k = 0; k < 8; ++k) {
                s += A[k].x * A[k].x + A[k].y * A[k].y + A[k].z * A[k].z + A[k].w * A[k].w;
                c += A[k].x * B[k].x + A[k].y * B[k].y + A[k].z * B[k].z + A[k].w * B[k].w;
            }
            sqv[i] = s; crv[i] = c;
        }
        // B holds row r0+i+1. Load row r0+i+2 into A.
        {
            int rr = r0 + i + 2; if (rr > N_ROWS - 1) rr = N_ROWS - 1;
            const int b = rr * 512 + lane;
            #pragma unroll
            for (int k = 0; k < 8; ++k) A[k] = ntload(&rowp[b + k * 64]);
        }
        {
            float s = 0.f, c = 0.f;
            #pragma unroll
            for (int k = 0; k < 8; ++k) {
                s += B[k].x * B[k].x + B[k].y * B[k].y + B[k].z * B[k].z + B[k].w * B[k].w;
                c += B[k].x * A[k].x + B[k].y * A[k].y + B[k].z * A[k].z + B[k].w * A[k].w;
            }
            sqv[i + 1] = s; crv[i + 1] = c;
        }
    }

    // Batched butterfly: independent 6-step chains, offset order 32..1 per value
    // (same as passing kernel -> bit-identical).
    #pragma unroll
    for (int off = 32; off; off >>= 1) {
        #pragma unroll
        for (int i = 0; i < RPW; ++i) {
            sqv[i] += __shfl_xor(sqv[i], off, 64);
            crv[i] += __shfl_xor(crv[i], off, 64);
        }
    }
    if (lane == 0) {
        #pragma unroll
        for (int i = 0; i < RPW; ++i) {
            sq[r0 + i]    = sqv[i];
            cross[r0 + i] = crv[i];
        }
    }
}

// Final reduction: sum cross[i] / (max(sqrt(sq[i]),eps) * max(sqrt(sq[i+1]),eps)),
// scale, atomic-accumulate into the fp32 scalar output. fp64 accumulation: the
// sum has heavy cancellation (65535 terms ~±0.02 netting ~0.4). UNCHANGED.
__global__ __launch_bounds__(256) void tcr_pass2(const float* __restrict__ sq,
                                                 const float* __restrict__ cross,
                                                 float* __restrict__ out) {
    const int tid    = blockIdx.x * 256 + threadIdx.x;
    const int stride = gridDim.x * 256;
    double acc = 0.0;
    for (int i = tid; i < N_ROWS - 1; i += stride) {
        double ni = fmax(sqrt((double)sq[i]),     1e-12);
        double nj = fmax(sqrt((double)sq[i + 1]), 1e-12);
        acc += (double)cross[i] / (ni * nj);
    }
    __shared__ double sd[256];
    sd[threadIdx.x] = acc;
    __syncthreads();
    for (int s = 128; s; s >>= 1) {
        if (threadIdx.x < s) sd[threadIdx.x] += sd[threadIdx.x + s];
        __syncthreads();
    }
    if (threadIdx.x == 0) {
        // out = -WEIGHT * (p1 + p2) = -0.01 * 2 * sum/(N-1)
        double partial = sd[0] * (-2.0 * 0.01 / (double)(N_ROWS - 1));
        atomicAdd(out, (float)partial);
    }
}

extern "C" void kernel_launch(void* const* d_in, const int* in_sizes, int n_in,
                              void* d_out, int out_size, void* d_ws, size_t ws_size,
                              hipStream_t stream) {
    const float* factor = (const float*)d_in[0];
    float* out = (float*)d_out;

    // Workspace layout: sq[N_ROWS] floats, then cross[N_ROWS] floats (cross[N-1] unused).
    float* sq    = (float*)d_ws;
    float* cross = sq + N_ROWS;

    // Pass 1: 65536 rows / 8 rows-per-wave = 8192 waves = 2048 blocks of 4 waves.
    const int n_waves  = N_ROWS / RPW;
    const int n_blocks = n_waves / 4;
    tcr_pass1<<<n_blocks, 256, 0, stream>>>(factor, sq, cross);

    // Zero the output scalar (harness poisons it to 0xAA before every timed call).
    hipMemsetAsync(d_out, 0, sizeof(float), stream);

    // Pass 2: tiny reduction over 65535 pairs.
    tcr_pass2<<<64, 256, 0, stream>>>(sq, cross, out);
}